// Round 8
// baseline (386.917 us; speedup 1.0000x reference)
//
#include <hip/hip_runtime.h>
#include <hip/hip_bf16.h>

#define DD 256
#define BB 2048
#define BM 128                   // c3 rows per tile
#define BN 32                    // batch columns per pipeline stage
#define NBLK 1024                // 512 tiles x 2 k-halves
#define NSTAGE (BB / BN)         // 64 pipeline iterations

typedef __bf16 bf16x8 __attribute__((ext_vector_type(8)));
typedef float  f32x4  __attribute__((ext_vector_type(4)));

#define AS1 __attribute__((address_space(1)))
#define AS3 __attribute__((address_space(3)))

__device__ __forceinline__ unsigned short f2bf(float f) {
    unsigned int u = __float_as_uint(f);
    return (unsigned short)((u + 0x7FFFu + ((u >> 16) & 1u)) >> 16);  // RNE
}
__device__ __forceinline__ float bf2f(unsigned short s) {
    return __uint_as_float(((unsigned int)s) << 16);
}
__device__ __forceinline__ void async_cp16(const void* g, void* l) {
    __builtin_amdgcn_global_load_lds((const AS1 unsigned int*)g,
                                     (AS3 unsigned int*)l, 16, 0, 0);
}

// K1: rel = x - offsets (fp32 + bf16), one float4 per thread
__global__ void prep_rel(const float* __restrict__ x, const float* __restrict__ offsets,
                         float* __restrict__ rel_f32, unsigned short* __restrict__ rel_bf16) {
    const int fi = blockIdx.x * 256 + threadIdx.x;      // 131072 float4 groups
    const int d4 = fi & 63;
    const float4 o4 = ((const float4*)offsets)[d4];
    const float4 x4 = ((const float4*)x)[fi];
    float4 r;
    r.x = x4.x - o4.x; r.y = x4.y - o4.y; r.z = x4.z - o4.z; r.w = x4.w - o4.w;
    ((float4*)rel_f32)[fi] = r;
    ushort4 rb;
    rb.x = f2bf(r.x); rb.y = f2bf(r.y); rb.z = f2bf(r.z); rb.w = f2bf(r.w);
    ((ushort4*)rel_bf16)[fi] = rb;
}

// K3: fused GEMM (c3 tile-khalf @ rel^T) + c2 fold + weighted column reduction.
// Grid 1024 = 512 tiles x 2 k-halves. 256 thr = 4 waves (wm2 rows x wk2 k-quarters).
// Wave: 64 rows x 32 cols x 64 k. afr 32 + acc 32 regs -> safe at 4 blocks/CU.
__global__ __launch_bounds__(256, 4) void taylor3(
    const float* __restrict__ c3, const float* __restrict__ c2,
    const float* __restrict__ rel_f32, const unsigned short* __restrict__ rel_bf16,
    float* __restrict__ partial)
{
    __shared__ unsigned short Bs[2][BN * 128];   // 2 x 8 KB, double-buffered (k-half only)
    __shared__ float c2row[BM];                  // 512 B
    __shared__ float colsum[2][4][BN];           // 1 KB

    const int bid  = blockIdx.x;
    const int tile = bid >> 1;
    const int kh   = bid & 1;                    // k-half: 0 -> k 0..127, 1 -> 128..255
    const int i_t   = tile >> 1;
    const int jbase = (tile & 1) << 7;
    const int tid  = threadIdx.x;
    const int wave = tid >> 6;
    const int lane = tid & 63;
    const int wm = wave & 1, wk = wave >> 1;
    const int lrow = lane & 15, quad = lane >> 4;

    if (tid < BM) c2row[tid] = c2[i_t * DD + jbase + tid];

    // ---- hoist A fragments: 64 rows (mt=4) x 64-k quarter -> 32 VGPRs ----
    bf16x8 afr[2][4];
    {
        const float* abase = c3 + (size_t)tile * BM * DD;
        const int koff = kh * 128 + wk * 64 + quad * 8;
#pragma unroll
        for (int mt = 0; mt < 4; ++mt) {
            const int row = wm * 64 + mt * 16 + lrow;
            const float* p = abase + (size_t)row * DD + koff;
#pragma unroll
            for (int ks = 0; ks < 2; ++ks) {
                float4 f0 = *(const float4*)(p + ks * 32);
                float4 f1 = *(const float4*)(p + ks * 32 + 4);
                union { unsigned short u[8]; bf16x8 v; } cv;
                cv.u[0] = f2bf(f0.x); cv.u[1] = f2bf(f0.y);
                cv.u[2] = f2bf(f0.z); cv.u[3] = f2bf(f0.w);
                cv.u[4] = f2bf(f1.x); cv.u[5] = f2bf(f1.y);
                cv.u[6] = f2bf(f1.z); cv.u[7] = f2bf(f1.w);
                afr[ks][mt] = cv.v;
            }
        }
    }

    // ---- async stage: rel[b-tile, k-half] -> Bs[buf]; 2 calls x 16 rows ----
    // LDS row layout: 128 k = 16 granules of 8 elems; phys granule = logical ^ (row & 15)
    auto stage = [&](int nb, int buf) {
        const int b0 = nb * BN;
#pragma unroll
        for (int c = 0; c < 2; ++c) {
            const int r0 = c * 16 + wave * 4;            // wave-uniform base row
            const int row = r0 + (lane >> 4);
            const int gsrc = (lane & 15) ^ (row & 15);
            const unsigned short* src = rel_bf16 + (size_t)(b0 + row) * DD + kh * 128 + gsrc * 8;
            async_cp16(src, &Bs[buf][r0 * 128]);
        }
    };

    stage(0, 0);
    int prev_b0 = -1;

    for (int nb = 0; nb < NSTAGE; ++nb) {
        const int cur = nb & 1;
        const int b0 = nb * BN;
        __syncthreads();          // drains async loads of Bs[cur]; WAR-protects Bs[cur^1]
        if (nb + 1 < NSTAGE) stage(nb + 1, cur ^ 1);

        // combine previous iteration's colsum while this iteration computes
        if (prev_b0 >= 0 && tid < BN) {
            const float v = colsum[cur ^ 1][0][tid] + colsum[cur ^ 1][1][tid]
                          + colsum[cur ^ 1][2][tid] + colsum[cur ^ 1][3][tid];
            const float relI = rel_f32[(size_t)(prev_b0 + tid) * DD + i_t];
            partial[(size_t)bid * BB + prev_b0 + tid] = relI * v;
        }

        // early-issue epilogue rel reads from global (L2-hot), independent of MFMA
        ushort4 rj[2][4];
#pragma unroll
        for (int nt = 0; nt < 2; ++nt) {
            const int bg = b0 + nt * 16 + lrow;
#pragma unroll
            for (int mt = 0; mt < 4; ++mt) {
                const int e = jbase + wm * 64 + mt * 16 + quad * 4;
                rj[nt][mt] = *(const ushort4*)(rel_bf16 + (size_t)bg * DD + e);
            }
        }

        f32x4 acc[4][2];
#pragma unroll
        for (int mt = 0; mt < 4; ++mt)
#pragma unroll
            for (int nt = 0; nt < 2; ++nt)
                acc[mt][nt] = (f32x4){0.f, 0.f, 0.f, 0.f};

        // ---- K-loop: 2 steps of 16x16x32 over this wave's 64-k quarter ----
#pragma unroll
        for (int ks = 0; ks < 2; ++ks) {
            const int glog = wk * 8 + ks * 4 + quad;
            bf16x8 bfr[2];
#pragma unroll
            for (int nt = 0; nt < 2; ++nt) {
                const int col = nt * 16 + lrow;
                const int g = glog ^ (col & 15);
                bfr[nt] = *(const bf16x8*)(&Bs[cur][col * 128 + g * 8]);
            }
#pragma unroll
            for (int mt = 0; mt < 4; ++mt)
#pragma unroll
                for (int nt = 0; nt < 2; ++nt)
                    acc[mt][nt] = __builtin_amdgcn_mfma_f32_16x16x32_bf16(
                        afr[ks][mt], bfr[nt], acc[mt][nt], 0, 0, 0);
        }

        // ---- epilogue: s(col) = sum_rows (G_part + c2?) * r[b, j(row)]; butterfly ----
        const bool addc2 = (kh == 0) && (wk == 0);
        float sv[2];
#pragma unroll
        for (int nt = 0; nt < 2; ++nt) {
            float s = 0.f;
#pragma unroll
            for (int mt = 0; mt < 4; ++mt) {
                const int el = wm * 64 + mt * 16 + quad * 4;
                float c2x = 0.f, c2y = 0.f, c2z = 0.f, c2w = 0.f;
                if (addc2) {   // wave-uniform branch
                    const float4 c2r = *(const float4*)(&c2row[el]);
                    c2x = c2r.x; c2y = c2r.y; c2z = c2r.z; c2w = c2r.w;
                }
                const ushort4 r4 = rj[nt][mt];
                s += (acc[mt][nt][0] + c2x) * bf2f(r4.x);
                s += (acc[mt][nt][1] + c2y) * bf2f(r4.y);
                s += (acc[mt][nt][2] + c2z) * bf2f(r4.z);
                s += (acc[mt][nt][3] + c2w) * bf2f(r4.w);
            }
            s += __shfl_xor(s, 16, 64);
            s += __shfl_xor(s, 32, 64);   // all lanes hold the column total
            sv[nt] = s;
        }
        if (lane < 32) colsum[cur][wave][lane] = (lane >> 4) ? sv[1] : sv[0];
        prev_b0 = b0;
    }
    __syncthreads();
    if (tid < BN) {   // final combine, parity (NSTAGE-1)&1 = 1
        const float v = colsum[1][0][tid] + colsum[1][1][tid]
                      + colsum[1][2][tid] + colsum[1][3][tid];
        const float relI = rel_f32[(size_t)(prev_b0 + tid) * DD + i_t];
        partial[(size_t)bid * BB + prev_b0 + tid] = relI * v;
    }
}

// K4: out[b] = c0 + <c1, rel_b> + sum over 1024 partial rows. 128 blocks x 16 b's.
__global__ void reduce_partial(const float* __restrict__ partial,
                               const float* __restrict__ rel_f32,
                               const float* __restrict__ c0, const float* __restrict__ c1,
                               float* __restrict__ out) {
    __shared__ float red[256];
    __shared__ float red2[256];
    const int t = threadIdx.x;
    const int bl = t & 15;                    // b within block's group of 16
    const int slice = t >> 4;                 // 16 slices x 64 partial rows
    const int bbase = blockIdx.x * 16;
    float s = 0.f;
    for (int i = 0; i < 64; ++i)
        s += partial[(size_t)(slice * 64 + i) * BB + bbase + bl];
    red[t] = s;
    // c1 dot: chunk = slice covers 16 elems of the 256-dim dot
    float d = 0.f;
#pragma unroll
    for (int e = 0; e < 16; ++e) {
        const int k = slice * 16 + e;
        d += c1[k] * rel_f32[(size_t)(bbase + bl) * DD + k];
    }
    red2[t] = d;
    __syncthreads();
    if (t < 128) { red[t] += red[t + 128]; red2[t] += red2[t + 128]; } __syncthreads();
    if (t < 64)  { red[t] += red[t + 64];  red2[t] += red2[t + 64];  } __syncthreads();
    if (t < 32)  { red[t] += red[t + 32];  red2[t] += red2[t + 32];  } __syncthreads();
    if (t < 16)  out[bbase + t] = c0[0] + red[t] + red[t + 16] + red2[t] + red2[t + 16];
}

extern "C" void kernel_launch(void* const* d_in, const int* in_sizes, int n_in,
                              void* d_out, int out_size, void* d_ws, size_t ws_size,
                              hipStream_t stream) {
    const float* x       = (const float*)d_in[0];
    const float* offsets = (const float*)d_in[1];
    const float* c0      = (const float*)d_in[2];
    const float* c1      = (const float*)d_in[3];
    const float* c2      = (const float*)d_in[4];
    const float* c3      = (const float*)d_in[5];
    float* out = (float*)d_out;

    char* ws = (char*)d_ws;
    float* rel_f32 = (float*)ws;                                             // 2 MB
    unsigned short* rel_bf16 = (unsigned short*)(ws + (size_t)BB * DD * 4);  // 1 MB
    float* partial = (float*)(ws + (size_t)BB * DD * 6);                     // 8 MB (1024 x 2048)

    prep_rel<<<512, 256, 0, stream>>>(x, offsets, rel_f32, rel_bf16);
    taylor3<<<NBLK, 256, 0, stream>>>(c3, c2, rel_f32, rel_bf16, partial);
    reduce_partial<<<128, 256, 0, stream>>>(partial, rel_f32, c0, c1, out);
}

// Round 9
// 333.568 us; speedup vs baseline: 1.1599x; 1.1599x over previous
//
#include <hip/hip_runtime.h>
#include <hip/hip_bf16.h>

#define DD 256
#define BB 2048
#define NT 1024                  // tiles: 65536 c3-rows / 64 rows per tile

typedef __bf16 bf16x8 __attribute__((ext_vector_type(8)));
typedef float  f32x4  __attribute__((ext_vector_type(4)));

__device__ __forceinline__ unsigned short f2bf(float f) {
    unsigned int u = __float_as_uint(f);
    return (unsigned short)((u + 0x7FFFu + ((u >> 16) & 1u)) >> 16);  // RNE
}
__device__ __forceinline__ float bf2f(unsigned short s) {
    return __uint_as_float(((unsigned int)s) << 16);
}

// K1: rel = x - offsets (fp32 + bf16), one float4 per thread
__global__ void prep_rel(const float* __restrict__ x, const float* __restrict__ offsets,
                         float* __restrict__ rel_f32, unsigned short* __restrict__ rel_bf16) {
    const int fi = blockIdx.x * 256 + threadIdx.x;      // 131072 float4 groups
    const int d4 = fi & 63;
    const float4 o4 = ((const float4*)offsets)[d4];
    const float4 x4 = ((const float4*)x)[fi];
    float4 r;
    r.x = x4.x - o4.x; r.y = x4.y - o4.y; r.z = x4.z - o4.z; r.w = x4.w - o4.w;
    ((float4*)rel_f32)[fi] = r;
    ushort4 rb;
    rb.x = f2bf(r.x); rb.y = f2bf(r.y); rb.z = f2bf(r.z); rb.w = f2bf(r.w);
    ((ushort4*)rel_bf16)[fi] = rb;
}

// K3: barrier-free fused GEMM + c2 fold + in-wave weighted row reduction.
// Grid 1024 tiles (64 c3-rows each). 4 fully independent waves per block; each
// wave owns ALL 64 rows x full K=256 and a rotating set of 32-column chunks.
// B-fragments read directly from L2-resident rel_bf16 (1 MB) — no LDS, no syncs.
__global__ __launch_bounds__(256, 2) void taylor3(
    const float* __restrict__ c3, const float* __restrict__ c2,
    const unsigned short* __restrict__ rel_bf16,
    float* __restrict__ partial)
{
    const int tile = blockIdx.x;
    const int i_t  = tile >> 2;          // i is constant across the 64-row tile
    const int jb   = (tile & 3) << 6;    // j window [jb, jb+64)
    const int lane = threadIdx.x & 63;
    const int wave = threadIdx.x >> 6;
    const int lrow = lane & 15, quad = lane >> 4;

    // ---- A fragments: 64 rows x 256 k, fp32->bf16 in-register (128 VGPRs) ----
    bf16x8 afr[8][4];
    {
        const float* abase = c3 + (size_t)tile * 64 * DD;
#pragma unroll
        for (int mt = 0; mt < 4; ++mt) {
            const float* p = abase + (size_t)(mt * 16 + lrow) * DD + quad * 8;
#pragma unroll
            for (int ks = 0; ks < 8; ++ks) {
                float4 f0 = *(const float4*)(p + ks * 32);
                float4 f1 = *(const float4*)(p + ks * 32 + 4);
                union { unsigned short u[8]; bf16x8 v; } cv;
                cv.u[0] = f2bf(f0.x); cv.u[1] = f2bf(f0.y);
                cv.u[2] = f2bf(f0.z); cv.u[3] = f2bf(f0.w);
                cv.u[4] = f2bf(f1.x); cv.u[5] = f2bf(f1.y);
                cv.u[6] = f2bf(f1.z); cv.u[7] = f2bf(f1.w);
                afr[ks][mt] = cv.v;
            }
        }
    }
    // c2 for this lane's 16 epilogue rows (C/D layout: local row = mt*16+quad*4+r)
    float4 c2v[4];
#pragma unroll
    for (int mt = 0; mt < 4; ++mt)
        c2v[mt] = *(const float4*)(c2 + (size_t)i_t * DD + jb + mt * 16 + quad * 4);

    // ---- column-chunk loop: wave w -> chunks w, w+4, ..., 60 (no inter-wave deps) ----
    for (int cb = wave; cb < 64; cb += 4) {
        const int b0 = cb * 32;

        // epilogue weights issued early (L1/L2-hot; overlaps MFMA)
        ushort4 rj[2][4];
#pragma unroll
        for (int nt = 0; nt < 2; ++nt) {
            const size_t rbase = (size_t)(b0 + nt * 16 + lrow) * DD;
#pragma unroll
            for (int mt = 0; mt < 4; ++mt)
                rj[nt][mt] = *(const ushort4*)(rel_bf16 + rbase + jb + mt * 16 + quad * 4);
        }

        f32x4 acc[4][2];
#pragma unroll
        for (int mt = 0; mt < 4; ++mt)
#pragma unroll
            for (int nt = 0; nt < 2; ++nt)
                acc[mt][nt] = (f32x4){0.f, 0.f, 0.f, 0.f};

        // ---- K-loop: B-frags straight from global (16 rows x 64 B, coalesced) ----
#pragma unroll
        for (int ks = 0; ks < 8; ++ks) {
            bf16x8 bfr[2];
#pragma unroll
            for (int nt = 0; nt < 2; ++nt)
                bfr[nt] = *(const bf16x8*)(rel_bf16 +
                    (size_t)(b0 + nt * 16 + lrow) * DD + ks * 32 + quad * 8);
#pragma unroll
            for (int mt = 0; mt < 4; ++mt)
#pragma unroll
                for (int nt = 0; nt < 2; ++nt)
                    acc[mt][nt] = __builtin_amdgcn_mfma_f32_16x16x32_bf16(
                        afr[ks][mt], bfr[nt], acc[mt][nt], 0, 0, 0);
        }

        // ---- epilogue: s(col) = sum_rows (G + c2) * r[b, j(row)]; quad butterfly ----
        float sv[2];
#pragma unroll
        for (int nt = 0; nt < 2; ++nt) {
            float s = 0.f;
#pragma unroll
            for (int mt = 0; mt < 4; ++mt) {
                const ushort4 r4 = rj[nt][mt];
                s += (acc[mt][nt][0] + c2v[mt].x) * bf2f(r4.x);
                s += (acc[mt][nt][1] + c2v[mt].y) * bf2f(r4.y);
                s += (acc[mt][nt][2] + c2v[mt].z) * bf2f(r4.z);
                s += (acc[mt][nt][3] + c2v[mt].w) * bf2f(r4.w);
            }
            s += __shfl_xor(s, 16, 64);
            s += __shfl_xor(s, 32, 64);   // all quads now hold the full column sum
            sv[nt] = s;
        }
        if (lane < 32)   // col = b0 + lane; value from sv[lane>>4]
            partial[(size_t)tile * BB + b0 + lane] = (lane >> 4) ? sv[1] : sv[0];
    }
}

// K4: out[b] = c0 + <c1, rel_b> + sum_t rel[b, t>>2] * partial[t][b].
// 32 blocks x 256 threads; block covers 64 b's, 4 tile-slices each.
__global__ void reduce_partial(const float* __restrict__ partial,
                               const float* __restrict__ rel_f32,
                               const float* __restrict__ c0, const float* __restrict__ c1,
                               float* __restrict__ out) {
    __shared__ float red[256];
    const int t = threadIdx.x;
    const int bl = t & 63;
    const int rs = t >> 6;                    // 4 slices of 256 tiles / 64 i-values
    const int b = blockIdx.x * 64 + bl;
    float s = 0.f;
    for (int g = rs * 64; g < rs * 64 + 64; ++g) {       // i value
        const float w = rel_f32[(size_t)b * DD + g];
#pragma unroll
        for (int q = 0; q < 4; ++q)                      // 4 tiles share this i
            s += w * partial[(size_t)(g * 4 + q) * BB + b];
    }
    float d = 0.f;                            // c1-dot chunk
#pragma unroll
    for (int k = rs * 64; k < rs * 64 + 64; ++k)
        d += c1[k] * rel_f32[(size_t)b * DD + k];
    red[t] = s + d;
    __syncthreads();
    if (t < 128) red[t] += red[t + 128];
    __syncthreads();
    if (t < 64) out[blockIdx.x * 64 + t] = c0[0] + red[t] + red[t + 64];
}

extern "C" void kernel_launch(void* const* d_in, const int* in_sizes, int n_in,
                              void* d_out, int out_size, void* d_ws, size_t ws_size,
                              hipStream_t stream) {
    const float* x       = (const float*)d_in[0];
    const float* offsets = (const float*)d_in[1];
    const float* c0      = (const float*)d_in[2];
    const float* c1      = (const float*)d_in[3];
    const float* c2      = (const float*)d_in[4];
    const float* c3      = (const float*)d_in[5];
    float* out = (float*)d_out;

    char* ws = (char*)d_ws;
    float* rel_f32 = (float*)ws;                                             // 2 MB
    unsigned short* rel_bf16 = (unsigned short*)(ws + (size_t)BB * DD * 4);  // 1 MB
    float* partial = (float*)(ws + (size_t)BB * DD * 6);                     // 8 MB (1024 x 2048)

    prep_rel<<<512, 256, 0, stream>>>(x, offsets, rel_f32, rel_bf16);
    taylor3<<<NT, 256, 0, stream>>>(c3, c2, rel_bf16, partial);
    reduce_partial<<<32, 256, 0, stream>>>(partial, rel_f32, c0, c1, out);
}